// Round 1
// baseline (1781.925 us; speedup 1.0000x reference)
//
#include <hip/hip_runtime.h>
#include <math.h>

#define N_NODES 20000
#define N_EDGES 320000
#define IN_CH   256
#define HID_CH  256
#define OUT_CH  128

// ---------------------------------------------------------------------------
// degree (indegree + 1 self-loop) -> dinv = 1/sqrt(deg)
// ---------------------------------------------------------------------------
__global__ void deg_kernel(const int* __restrict__ col, int* __restrict__ deg, int E) {
    int i = blockIdx.x * blockDim.x + threadIdx.x;
    if (i < E) atomicAdd(&deg[col[i]], 1);
}

__global__ void dinv_kernel(const int* __restrict__ deg, float* __restrict__ dinv, int n) {
    int i = blockIdx.x * blockDim.x + threadIdx.x;
    if (i < n) dinv[i] = 1.0f / sqrtf((float)(deg[i] + 1));
}

// ---------------------------------------------------------------------------
// fp32 SIMT GEMM: C[M,N] = A[M,K] @ B[K,N]. 64x64 tile, BK=16, 256 thr, 4x4/thr.
// N, K multiples of 16/64 here (N in {256,128}, K=256); only M needs guards.
// ---------------------------------------------------------------------------
__global__ __launch_bounds__(256)
void gemm_kernel(const float* __restrict__ A, const float* __restrict__ B,
                 float* __restrict__ C, int M, int N, int K) {
    __shared__ float As[16][64];   // [k][m]
    __shared__ float Bs[16][64];   // [k][n]
    const int tid = threadIdx.x;
    const int tx = tid & 15;       // 0..15 -> 4 cols each
    const int ty = tid >> 4;       // 0..15 -> 4 rows each
    const int m0 = blockIdx.y * 64;
    const int n0 = blockIdx.x * 64;

    float acc[4][4] = {};

    const int arow = tid >> 2;        // 0..63
    const int acol = (tid & 3) * 4;   // 0,4,8,12
    const int brow = tid >> 4;        // 0..15
    const int bcol = (tid & 15) * 4;  // 0..60

    for (int k0 = 0; k0 < K; k0 += 16) {
        float4 av = make_float4(0.f, 0.f, 0.f, 0.f);
        if (m0 + arow < M)
            av = *(const float4*)(A + (size_t)(m0 + arow) * K + k0 + acol);
        As[acol + 0][arow] = av.x;
        As[acol + 1][arow] = av.y;
        As[acol + 2][arow] = av.z;
        As[acol + 3][arow] = av.w;
        float4 bv = *(const float4*)(B + (size_t)(k0 + brow) * N + n0 + bcol);
        *(float4*)(&Bs[brow][bcol]) = bv;
        __syncthreads();
#pragma unroll
        for (int k = 0; k < 16; ++k) {
            float a[4], b[4];
#pragma unroll
            for (int i = 0; i < 4; ++i) a[i] = As[k][ty * 4 + i];
#pragma unroll
            for (int j = 0; j < 4; ++j) b[j] = Bs[k][tx * 4 + j];
#pragma unroll
            for (int i = 0; i < 4; ++i)
#pragma unroll
                for (int j = 0; j < 4; ++j) acc[i][j] += a[i] * b[j];
        }
        __syncthreads();
    }

#pragma unroll
    for (int i = 0; i < 4; ++i) {
        int m = m0 + ty * 4 + i;
        if (m < M) {
            float4 v = make_float4(acc[i][0], acc[i][1], acc[i][2], acc[i][3]);
            *(float4*)(C + (size_t)m * N + n0 + tx * 4) = v;
        }
    }
}

// ---------------------------------------------------------------------------
// scatter: for each edge e, out[col[e]] += X[row[e]] * dinv[row]*dinv[col]
// tpe = C/4 threads per edge, one float4 per thread. shift = log2(tpe).
// ---------------------------------------------------------------------------
__global__ void scatter_kernel(const float* __restrict__ X, const float* __restrict__ dinv,
                               const int* __restrict__ row, const int* __restrict__ col,
                               float* __restrict__ out, int E, int C, int shift) {
    int gid = blockIdx.x * blockDim.x + threadIdx.x;
    int e = gid >> shift;
    int l = gid & ((1 << shift) - 1);
    if (e >= E) return;
    int r = row[e];
    int c = col[e];
    float w = dinv[r] * dinv[c];
    float4 v = *(const float4*)(X + (size_t)r * C + l * 4);
    float* dst = out + (size_t)c * C + l * 4;
    atomicAdd(dst + 0, v.x * w);
    atomicAdd(dst + 1, v.y * w);
    atomicAdd(dst + 2, v.z * w);
    atomicAdd(dst + 3, v.w * w);
}

// ---------------------------------------------------------------------------
// finalize: out = (relu?)(agg + X*dinv^2 + b). One float4 per thread.
// shift = log2(C/4). In-place safe (agg may alias out).
// ---------------------------------------------------------------------------
__global__ void finalize_kernel(const float* __restrict__ agg, const float* __restrict__ X,
                                const float* __restrict__ dinv, const float* __restrict__ b,
                                float* __restrict__ out, int n, int shift, int relu) {
    int gid = blockIdx.x * blockDim.x + threadIdx.x;
    int total = n << shift;
    if (gid >= total) return;
    int i = gid >> shift;
    int l = gid & ((1 << shift) - 1);
    float d = dinv[i];
    float w = d * d;
    float4 a  = *(const float4*)(agg + (size_t)gid * 4);
    float4 x  = *(const float4*)(X + (size_t)gid * 4);
    float4 bb = *(const float4*)(b + l * 4);
    float4 o;
    o.x = a.x + x.x * w + bb.x;
    o.y = a.y + x.y * w + bb.y;
    o.z = a.z + x.z * w + bb.z;
    o.w = a.w + x.w * w + bb.w;
    if (relu) {
        o.x = fmaxf(o.x, 0.f);
        o.y = fmaxf(o.y, 0.f);
        o.z = fmaxf(o.z, 0.f);
        o.w = fmaxf(o.w, 0.f);
    }
    *(float4*)(out + (size_t)gid * 4) = o;
}

// ---------------------------------------------------------------------------
extern "C" void kernel_launch(void* const* d_in, const int* in_sizes, int n_in,
                              void* d_out, int out_size, void* d_ws, size_t ws_size,
                              hipStream_t stream) {
    const float* doc_embeds = (const float*)d_in[0];   // [20000,256]
    const int*   edge_index = (const int*)d_in[1];     // [2,320000]
    const float* W1 = (const float*)d_in[2];           // [256,256]
    const float* b1 = (const float*)d_in[3];           // [256]
    const float* W2 = (const float*)d_in[4];           // [256,128]
    const float* b2 = (const float*)d_in[5];           // [128]
    float* out = (float*)d_out;                        // [20000,128]

    const int* row = edge_index;            // sources
    const int* col = edge_index + N_EDGES;  // destinations

    // workspace layout (bytes), 256-aligned
    char* ws = (char*)d_ws;
    const size_t X1_BYTES  = (size_t)N_NODES * HID_CH * 4;  // 20.48 MB (also reused for X2)
    const size_t AGG_BYTES = (size_t)N_NODES * HID_CH * 4;  // 20.48 MB
    float* X1   = (float*)(ws);
    float* AGG1 = (float*)(ws + X1_BYTES);
    int*   deg  = (int*)  (ws + X1_BYTES + AGG_BYTES);
    float* dinv = (float*)(ws + X1_BYTES + AGG_BYTES + ((size_t)N_NODES * 4 + 255) / 256 * 256);
    float* X2   = X1;  // reuse (gemm2 reads AGG1, writes X2)

    // 1) degrees + dinv
    hipMemsetAsync(deg, 0, (size_t)N_NODES * 4, stream);
    deg_kernel<<<(N_EDGES + 255) / 256, 256, 0, stream>>>(col, deg, N_EDGES);
    dinv_kernel<<<(N_NODES + 255) / 256, 256, 0, stream>>>(deg, dinv, N_NODES);

    // 2) GEMM1: X1 = doc_embeds @ W1
    {
        dim3 grid(HID_CH / 64, (N_NODES + 63) / 64);
        gemm_kernel<<<grid, 256, 0, stream>>>(doc_embeds, W1, X1, N_NODES, HID_CH, IN_CH);
    }

    // 3) scatter layer 1 into AGG1
    hipMemsetAsync(AGG1, 0, AGG_BYTES, stream);
    {
        long long total = (long long)N_EDGES * (HID_CH / 4);
        scatter_kernel<<<(int)((total + 255) / 256), 256, 0, stream>>>(
            X1, dinv, row, col, AGG1, N_EDGES, HID_CH, 6);
    }

    // 4) finalize layer 1 (self loop + bias + relu), in place -> H1 = AGG1
    {
        int total = N_NODES * (HID_CH / 4);
        finalize_kernel<<<(total + 255) / 256, 256, 0, stream>>>(
            AGG1, X1, dinv, b1, AGG1, N_NODES, 6, 1);
    }

    // 5) GEMM2: X2 = H1 @ W2
    {
        dim3 grid(OUT_CH / 64, (N_NODES + 63) / 64);
        gemm_kernel<<<grid, 256, 0, stream>>>(AGG1, W2, X2, N_NODES, OUT_CH, HID_CH);
    }

    // 6) scatter layer 2 into d_out
    hipMemsetAsync(out, 0, (size_t)N_NODES * OUT_CH * 4, stream);
    {
        long long total = (long long)N_EDGES * (OUT_CH / 4);
        scatter_kernel<<<(int)((total + 255) / 256), 256, 0, stream>>>(
            X2, dinv, row, col, out, N_EDGES, OUT_CH, 5);
    }

    // 7) finalize layer 2 (self loop + bias), in place on d_out
    {
        int total = N_NODES * (OUT_CH / 4);
        finalize_kernel<<<(total + 255) / 256, 256, 0, stream>>>(
            out, X2, dinv, b2, out, N_NODES, 5, 0);
    }
}

// Round 2
// 318.475 us; speedup vs baseline: 5.5952x; 5.5952x over previous
//
#include <hip/hip_runtime.h>
#include <math.h>

#define N_NODES 20000
#define N_EDGES 320000
#define IN_CH   256
#define HID_CH  256
#define OUT_CH  128

// ---------------------------------------------------------------------------
// degree (indegree, self-loop added later) via int atomics
// ---------------------------------------------------------------------------
__global__ void deg_kernel(const int* __restrict__ col, int* __restrict__ deg, int E) {
    int i = blockIdx.x * blockDim.x + threadIdx.x;
    if (i < E) atomicAdd(&deg[col[i]], 1);
}

__global__ void dinv_kernel(const int* __restrict__ deg, float* __restrict__ dinv, int n) {
    int i = blockIdx.x * blockDim.x + threadIdx.x;
    if (i < n) dinv[i] = 1.0f / sqrtf((float)(deg[i] + 1));  // +1 self-loop
}

// ---------------------------------------------------------------------------
// single-block exclusive scan of deg[0..n) -> rowptr[0..n] and cursor copy
// 256 threads, each owns a contiguous chunk.
// ---------------------------------------------------------------------------
__global__ __launch_bounds__(256)
void scan_kernel(const int* __restrict__ deg, int* __restrict__ rowptr,
                 int* __restrict__ cursor, int n) {
    __shared__ int sums[256];
    const int tid = threadIdx.x;
    const int per = (n + 255) / 256;
    const int base = tid * per;
    int s = 0;
    for (int i = 0; i < per; ++i) {
        int idx = base + i;
        if (idx < n) s += deg[idx];
    }
    sums[tid] = s;
    __syncthreads();
    // Hillis-Steele inclusive scan over 256 partials
    for (int off = 1; off < 256; off <<= 1) {
        int v = 0;
        if (tid >= off) v = sums[tid - off];
        __syncthreads();
        if (tid >= off) sums[tid] += v;
        __syncthreads();
    }
    int run = (tid == 0) ? 0 : sums[tid - 1];
    for (int i = 0; i < per; ++i) {
        int idx = base + i;
        if (idx < n) {
            rowptr[idx] = run;
            cursor[idx] = run;
            run += deg[idx];
        }
    }
    if (tid == 255) rowptr[n] = run;  // == E (all real elements covered by earlier threads)
}

// ---------------------------------------------------------------------------
// fill CSR: srcs[pos] = row[e], bucketed by destination col[e]
// ---------------------------------------------------------------------------
__global__ void fill_kernel(const int* __restrict__ row, const int* __restrict__ col,
                            int* __restrict__ cursor, int* __restrict__ srcs, int E) {
    int i = blockIdx.x * blockDim.x + threadIdx.x;
    if (i < E) {
        int p = atomicAdd(&cursor[col[i]], 1);
        srcs[p] = row[i];
    }
}

// ---------------------------------------------------------------------------
// fp32 SIMT GEMM: C[M,N] = A[M,K] @ B[K,N]. 64x64 tile, BK=16, 256 thr, 4x4/thr.
// ---------------------------------------------------------------------------
__global__ __launch_bounds__(256)
void gemm_kernel(const float* __restrict__ A, const float* __restrict__ B,
                 float* __restrict__ C, int M, int N, int K) {
    __shared__ float As[16][64];   // [k][m]
    __shared__ float Bs[16][64];   // [k][n]
    const int tid = threadIdx.x;
    const int tx = tid & 15;
    const int ty = tid >> 4;
    const int m0 = blockIdx.y * 64;
    const int n0 = blockIdx.x * 64;

    float acc[4][4] = {};

    const int arow = tid >> 2;
    const int acol = (tid & 3) * 4;
    const int brow = tid >> 4;
    const int bcol = (tid & 15) * 4;

    for (int k0 = 0; k0 < K; k0 += 16) {
        float4 av = make_float4(0.f, 0.f, 0.f, 0.f);
        if (m0 + arow < M)
            av = *(const float4*)(A + (size_t)(m0 + arow) * K + k0 + acol);
        As[acol + 0][arow] = av.x;
        As[acol + 1][arow] = av.y;
        As[acol + 2][arow] = av.z;
        As[acol + 3][arow] = av.w;
        float4 bv = *(const float4*)(B + (size_t)(k0 + brow) * N + n0 + bcol);
        *(float4*)(&Bs[brow][bcol]) = bv;
        __syncthreads();
#pragma unroll
        for (int k = 0; k < 16; ++k) {
            float a[4], b[4];
#pragma unroll
            for (int i = 0; i < 4; ++i) a[i] = As[k][ty * 4 + i];
#pragma unroll
            for (int j = 0; j < 4; ++j) b[j] = Bs[k][tx * 4 + j];
#pragma unroll
            for (int i = 0; i < 4; ++i)
#pragma unroll
                for (int j = 0; j < 4; ++j) acc[i][j] += a[i] * b[j];
        }
        __syncthreads();
    }

#pragma unroll
    for (int i = 0; i < 4; ++i) {
        int m = m0 + ty * 4 + i;
        if (m < M) {
            float4 v = make_float4(acc[i][0], acc[i][1], acc[i][2], acc[i][3]);
            *(float4*)(C + (size_t)m * N + n0 + tx * 4) = v;
        }
    }
}

// ---------------------------------------------------------------------------
// gather aggregation: one wave per destination node. Each lane holds VEC
// consecutive channels (VEC=4 -> 256ch, VEC=2 -> 128ch). Register accumulate,
// single write. Epilogue folds self-loop + bias (+relu):
//   out[c] = relu( dinv[c] * ( sum_r dinv[r]*X[r] + dinv[c]*X[c] ) + b )
// ---------------------------------------------------------------------------
template <int VEC>
__global__ __launch_bounds__(256)
void gather_kernel(const float* __restrict__ X, const float* __restrict__ dinv,
                   const int* __restrict__ rowptr, const int* __restrict__ srcs,
                   const float* __restrict__ bias, float* __restrict__ out,
                   int n, int relu) {
    const int C = VEC * 64;
    const int wave = blockIdx.x * (blockDim.x >> 6) + (threadIdx.x >> 6);
    const int lane = threadIdx.x & 63;
    if (wave >= n) return;
    const int beg = rowptr[wave];
    const int end = rowptr[wave + 1];

    float acc[VEC];
#pragma unroll
    for (int i = 0; i < VEC; ++i) acc[i] = 0.f;

    for (int e = beg; e < end; ++e) {
        int r = srcs[e];
        float w = dinv[r];  // same addr across wave -> broadcast
        const float* xp = X + (size_t)r * C + lane * VEC;
        if constexpr (VEC == 4) {
            float4 v = *(const float4*)xp;
            acc[0] += w * v.x; acc[1] += w * v.y;
            acc[2] += w * v.z; acc[3] += w * v.w;
        } else {
            float2 v = *(const float2*)xp;
            acc[0] += w * v.x; acc[1] += w * v.y;
        }
    }

    const float dc = dinv[wave];
    const float* xs = X + (size_t)wave * C + lane * VEC;
    const float* bp = bias + lane * VEC;
    float* op = out + (size_t)wave * C + lane * VEC;

    float o[VEC];
    if constexpr (VEC == 4) {
        float4 vs = *(const float4*)xs;
        float4 bb = *(const float4*)bp;
        o[0] = dc * (acc[0] + dc * vs.x) + bb.x;
        o[1] = dc * (acc[1] + dc * vs.y) + bb.y;
        o[2] = dc * (acc[2] + dc * vs.z) + bb.z;
        o[3] = dc * (acc[3] + dc * vs.w) + bb.w;
    } else {
        float2 vs = *(const float2*)xs;
        float2 bb = *(const float2*)bp;
        o[0] = dc * (acc[0] + dc * vs.x) + bb.x;
        o[1] = dc * (acc[1] + dc * vs.y) + bb.y;
    }
    if (relu) {
#pragma unroll
        for (int i = 0; i < VEC; ++i) o[i] = fmaxf(o[i], 0.f);
    }
    if constexpr (VEC == 4) {
        *(float4*)op = make_float4(o[0], o[1], o[2], o[3]);
    } else {
        *(float2*)op = make_float2(o[0], o[1]);
    }
}

// ---------------------------------------------------------------------------
extern "C" void kernel_launch(void* const* d_in, const int* in_sizes, int n_in,
                              void* d_out, int out_size, void* d_ws, size_t ws_size,
                              hipStream_t stream) {
    const float* doc_embeds = (const float*)d_in[0];   // [20000,256]
    const int*   edge_index = (const int*)d_in[1];     // [2,320000]
    const float* W1 = (const float*)d_in[2];           // [256,256]
    const float* b1 = (const float*)d_in[3];           // [256]
    const float* W2 = (const float*)d_in[4];           // [256,128]
    const float* b2 = (const float*)d_in[5];           // [128]
    float* out = (float*)d_out;                        // [20000,128]

    const int* row = edge_index;            // sources
    const int* col = edge_index + N_EDGES;  // destinations

    // workspace layout, 256B aligned
    char* ws = (char*)d_ws;
    const size_t X1_BYTES = (size_t)N_NODES * HID_CH * 4;  // 20.48 MB
    const size_t H1_BYTES = (size_t)N_NODES * HID_CH * 4;  // 20.48 MB
    float* X1   = (float*)(ws);
    float* H1   = (float*)(ws + X1_BYTES);
    char*  meta = ws + X1_BYTES + H1_BYTES;
    int*   deg    = (int*)(meta);                    meta += ((size_t)N_NODES * 4 + 255) / 256 * 256;
    int*   rowptr = (int*)(meta);                    meta += ((size_t)(N_NODES + 1) * 4 + 255) / 256 * 256;
    int*   cursor = (int*)(meta);                    meta += ((size_t)(N_NODES + 1) * 4 + 255) / 256 * 256;
    float* dinv   = (float*)(meta);                  meta += ((size_t)N_NODES * 4 + 255) / 256 * 256;
    int*   srcs   = (int*)(meta);
    float* X2     = X1;  // reuse: gemm2 reads H1, writes X2

    // 1) graph prep: deg -> dinv, rowptr/cursor, CSR fill
    hipMemsetAsync(deg, 0, (size_t)N_NODES * 4, stream);
    deg_kernel<<<(N_EDGES + 255) / 256, 256, 0, stream>>>(col, deg, N_EDGES);
    dinv_kernel<<<(N_NODES + 255) / 256, 256, 0, stream>>>(deg, dinv, N_NODES);
    scan_kernel<<<1, 256, 0, stream>>>(deg, rowptr, cursor, N_NODES);
    fill_kernel<<<(N_EDGES + 255) / 256, 256, 0, stream>>>(row, col, cursor, srcs, N_EDGES);

    // 2) GEMM1: X1 = doc_embeds @ W1
    {
        dim3 grid(HID_CH / 64, (N_NODES + 63) / 64);
        gemm_kernel<<<grid, 256, 0, stream>>>(doc_embeds, W1, X1, N_NODES, HID_CH, IN_CH);
    }

    // 3) gather layer 1 (+self-loop +bias +relu) -> H1
    gather_kernel<4><<<(N_NODES + 3) / 4, 256, 0, stream>>>(
        X1, dinv, rowptr, srcs, b1, H1, N_NODES, 1);

    // 4) GEMM2: X2 = H1 @ W2
    {
        dim3 grid(OUT_CH / 64, (N_NODES + 63) / 64);
        gemm_kernel<<<grid, 256, 0, stream>>>(H1, W2, X2, N_NODES, OUT_CH, HID_CH);
    }

    // 5) gather layer 2 (+self-loop +bias) -> d_out
    gather_kernel<2><<<(N_NODES + 3) / 4, 256, 0, stream>>>(
        X2, dinv, rowptr, srcs, b2, out, N_NODES, 0);
}

// Round 3
// 270.415 us; speedup vs baseline: 6.5896x; 1.1777x over previous
//
#include <hip/hip_runtime.h>
#include <math.h>

#define N_NODES 20000
#define N_EDGES 320000
#define IN_CH   256
#define HID_CH  256
#define OUT_CH  128

#define SCAN_TILE 256
#define N_TILES ((N_NODES + SCAN_TILE - 1) / SCAN_TILE)   // 79

// ---------------------------------------------------------------------------
// degree (indegree, self-loop handled in dinv) via int atomics
// ---------------------------------------------------------------------------
__global__ void deg_kernel(const int* __restrict__ col, int* __restrict__ deg, int E) {
    int i = blockIdx.x * blockDim.x + threadIdx.x;
    if (i < E) atomicAdd(&deg[col[i]], 1);
}

// ---------------------------------------------------------------------------
// phase 1: per-tile exclusive scan (LDS Hillis-Steele) + tile partial sums
// ---------------------------------------------------------------------------
__global__ __launch_bounds__(SCAN_TILE)
void block_scan_kernel(const int* __restrict__ deg, int* __restrict__ tile_excl,
                       int* __restrict__ partials, int n) {
    __shared__ int s[SCAN_TILE];
    const int tid = threadIdx.x;
    const int i = blockIdx.x * SCAN_TILE + tid;
    int v = (i < n) ? deg[i] : 0;
    s[tid] = v;
    __syncthreads();
    for (int off = 1; off < SCAN_TILE; off <<= 1) {
        int t = (tid >= off) ? s[tid - off] : 0;
        __syncthreads();
        if (tid >= off) s[tid] += t;
        __syncthreads();
    }
    if (i < n) tile_excl[i] = s[tid] - v;   // exclusive within tile
    if (tid == SCAN_TILE - 1) partials[blockIdx.x] = s[tid];
}

// ---------------------------------------------------------------------------
// phase 2: scan the N_TILES partials (single tiny block)
// ---------------------------------------------------------------------------
__global__ __launch_bounds__(128)
void partial_scan_kernel(const int* __restrict__ partials, int* __restrict__ offsets,
                         int ntiles) {
    __shared__ int s[128];
    const int tid = threadIdx.x;
    int v = (tid < ntiles) ? partials[tid] : 0;
    s[tid] = v;
    __syncthreads();
    for (int off = 1; off < 128; off <<= 1) {
        int t = (tid >= off) ? s[tid - off] : 0;
        __syncthreads();
        if (tid >= off) s[tid] += t;
        __syncthreads();
    }
    if (tid < ntiles) offsets[tid] = s[tid] - v;  // exclusive
}

// ---------------------------------------------------------------------------
// phase 3: rowptr/cursor = tile_excl + tile offset; fused dinv = rsqrt(deg+1)
// ---------------------------------------------------------------------------
__global__ __launch_bounds__(SCAN_TILE)
void finalize_scan_kernel(const int* __restrict__ tile_excl, const int* __restrict__ offsets,
                          const int* __restrict__ deg, int* __restrict__ rowptr,
                          int* __restrict__ cursor, float* __restrict__ dinv, int n) {
    const int i = blockIdx.x * SCAN_TILE + threadIdx.x;
    if (i < n) {
        int r = tile_excl[i] + offsets[blockIdx.x];
        rowptr[i] = r;
        cursor[i] = r;
        dinv[i] = 1.0f / sqrtf((float)(deg[i] + 1));
    }
    if (i == 0) rowptr[n] = N_EDGES;  // sum of degrees is the edge count
}

// ---------------------------------------------------------------------------
// fill CSR: srcs[pos] = row[e], bucketed by destination col[e]
// ---------------------------------------------------------------------------
__global__ void fill_kernel(const int* __restrict__ row, const int* __restrict__ col,
                            int* __restrict__ cursor, int* __restrict__ srcs, int E) {
    int i = blockIdx.x * blockDim.x + threadIdx.x;
    if (i < E) {
        int p = atomicAdd(&cursor[col[i]], 1);
        srcs[p] = row[i];
    }
}

// ---------------------------------------------------------------------------
// fp32 SIMT GEMM: C[M,N] = A[M,K] @ B[K,N]. 64x64 tile, BK=16, 256 thr, 4x4/thr.
// ---------------------------------------------------------------------------
__global__ __launch_bounds__(256)
void gemm_kernel(const float* __restrict__ A, const float* __restrict__ B,
                 float* __restrict__ C, int M, int N, int K) {
    __shared__ float As[16][64];   // [k][m]
    __shared__ float Bs[16][64];   // [k][n]
    const int tid = threadIdx.x;
    const int tx = tid & 15;
    const int ty = tid >> 4;
    const int m0 = blockIdx.y * 64;
    const int n0 = blockIdx.x * 64;

    float acc[4][4] = {};

    const int arow = tid >> 2;
    const int acol = (tid & 3) * 4;
    const int brow = tid >> 4;
    const int bcol = (tid & 15) * 4;

    for (int k0 = 0; k0 < K; k0 += 16) {
        float4 av = make_float4(0.f, 0.f, 0.f, 0.f);
        if (m0 + arow < M)
            av = *(const float4*)(A + (size_t)(m0 + arow) * K + k0 + acol);
        As[acol + 0][arow] = av.x;
        As[acol + 1][arow] = av.y;
        As[acol + 2][arow] = av.z;
        As[acol + 3][arow] = av.w;
        float4 bv = *(const float4*)(B + (size_t)(k0 + brow) * N + n0 + bcol);
        *(float4*)(&Bs[brow][bcol]) = bv;
        __syncthreads();
#pragma unroll
        for (int k = 0; k < 16; ++k) {
            float a[4], b[4];
#pragma unroll
            for (int i = 0; i < 4; ++i) a[i] = As[k][ty * 4 + i];
#pragma unroll
            for (int j = 0; j < 4; ++j) b[j] = Bs[k][tx * 4 + j];
#pragma unroll
            for (int i = 0; i < 4; ++i)
#pragma unroll
                for (int j = 0; j < 4; ++j) acc[i][j] += a[i] * b[j];
        }
        __syncthreads();
    }

#pragma unroll
    for (int i = 0; i < 4; ++i) {
        int m = m0 + ty * 4 + i;
        if (m < M) {
            float4 v = make_float4(acc[i][0], acc[i][1], acc[i][2], acc[i][3]);
            *(float4*)(C + (size_t)m * N + n0 + tx * 4) = v;
        }
    }
}

// ---------------------------------------------------------------------------
// gather aggregation: one wave per destination node. Each lane holds VEC
// consecutive channels (VEC=4 -> 256ch, VEC=2 -> 128ch). Register accumulate,
// single write. Epilogue folds self-loop + bias (+relu).
// ---------------------------------------------------------------------------
template <int VEC>
__global__ __launch_bounds__(256)
void gather_kernel(const float* __restrict__ X, const float* __restrict__ dinv,
                   const int* __restrict__ rowptr, const int* __restrict__ srcs,
                   const float* __restrict__ bias, float* __restrict__ out,
                   int n, int relu) {
    const int C = VEC * 64;
    const int wave = blockIdx.x * (blockDim.x >> 6) + (threadIdx.x >> 6);
    const int lane = threadIdx.x & 63;
    if (wave >= n) return;
    const int beg = rowptr[wave];
    const int end = rowptr[wave + 1];

    float acc[VEC];
#pragma unroll
    for (int i = 0; i < VEC; ++i) acc[i] = 0.f;

    for (int e = beg; e < end; ++e) {
        int r = srcs[e];
        float w = dinv[r];  // same addr across wave -> broadcast
        const float* xp = X + (size_t)r * C + lane * VEC;
        if constexpr (VEC == 4) {
            float4 v = *(const float4*)xp;
            acc[0] += w * v.x; acc[1] += w * v.y;
            acc[2] += w * v.z; acc[3] += w * v.w;
        } else {
            float2 v = *(const float2*)xp;
            acc[0] += w * v.x; acc[1] += w * v.y;
        }
    }

    const float dc = dinv[wave];
    const float* xs = X + (size_t)wave * C + lane * VEC;
    const float* bp = bias + lane * VEC;
    float* op = out + (size_t)wave * C + lane * VEC;

    float o[VEC];
    if constexpr (VEC == 4) {
        float4 vs = *(const float4*)xs;
        float4 bb = *(const float4*)bp;
        o[0] = dc * (acc[0] + dc * vs.x) + bb.x;
        o[1] = dc * (acc[1] + dc * vs.y) + bb.y;
        o[2] = dc * (acc[2] + dc * vs.z) + bb.z;
        o[3] = dc * (acc[3] + dc * vs.w) + bb.w;
    } else {
        float2 vs = *(const float2*)xs;
        float2 bb = *(const float2*)bp;
        o[0] = dc * (acc[0] + dc * vs.x) + bb.x;
        o[1] = dc * (acc[1] + dc * vs.y) + bb.y;
    }
    if (relu) {
#pragma unroll
        for (int i = 0; i < VEC; ++i) o[i] = fmaxf(o[i], 0.f);
    }
    if constexpr (VEC == 4) {
        *(float4*)op = make_float4(o[0], o[1], o[2], o[3]);
    } else {
        *(float2*)op = make_float2(o[0], o[1]);
    }
}

// ---------------------------------------------------------------------------
extern "C" void kernel_launch(void* const* d_in, const int* in_sizes, int n_in,
                              void* d_out, int out_size, void* d_ws, size_t ws_size,
                              hipStream_t stream) {
    const float* doc_embeds = (const float*)d_in[0];   // [20000,256]
    const int*   edge_index = (const int*)d_in[1];     // [2,320000]
    const float* W1 = (const float*)d_in[2];           // [256,256]
    const float* b1 = (const float*)d_in[3];           // [256]
    const float* W2 = (const float*)d_in[4];           // [256,128]
    const float* b2 = (const float*)d_in[5];           // [128]
    float* out = (float*)d_out;                        // [20000,128]

    const int* row = edge_index;            // sources
    const int* col = edge_index + N_EDGES;  // destinations

    // workspace layout, 256B aligned
    char* ws = (char*)d_ws;
    const size_t X1_BYTES = (size_t)N_NODES * HID_CH * 4;  // 20.48 MB
    const size_t H1_BYTES = (size_t)N_NODES * HID_CH * 4;  // 20.48 MB
    float* X1   = (float*)(ws);
    float* H1   = (float*)(ws + X1_BYTES);
    char*  meta = ws + X1_BYTES + H1_BYTES;
    auto align_up = [](size_t x) { return (x + 255) / 256 * 256; };
    int*   deg       = (int*)(meta);   meta += align_up((size_t)N_NODES * 4);
    int*   tile_excl = (int*)(meta);   meta += align_up((size_t)N_NODES * 4);
    int*   partials  = (int*)(meta);   meta += align_up((size_t)N_TILES * 4);
    int*   offsets   = (int*)(meta);   meta += align_up((size_t)N_TILES * 4);
    int*   rowptr    = (int*)(meta);   meta += align_up((size_t)(N_NODES + 1) * 4);
    int*   cursor    = (int*)(meta);   meta += align_up((size_t)(N_NODES + 1) * 4);
    float* dinv      = (float*)(meta); meta += align_up((size_t)N_NODES * 4);
    int*   srcs      = (int*)(meta);
    float* X2        = X1;  // reuse: gemm2 reads H1, writes X2

    // 1) graph prep: deg -> multi-block scan -> rowptr/cursor/dinv -> CSR fill
    hipMemsetAsync(deg, 0, (size_t)N_NODES * 4, stream);
    deg_kernel<<<(N_EDGES + 255) / 256, 256, 0, stream>>>(col, deg, N_EDGES);
    block_scan_kernel<<<N_TILES, SCAN_TILE, 0, stream>>>(deg, tile_excl, partials, N_NODES);
    partial_scan_kernel<<<1, 128, 0, stream>>>(partials, offsets, N_TILES);
    finalize_scan_kernel<<<N_TILES, SCAN_TILE, 0, stream>>>(
        tile_excl, offsets, deg, rowptr, cursor, dinv, N_NODES);
    fill_kernel<<<(N_EDGES + 255) / 256, 256, 0, stream>>>(row, col, cursor, srcs, N_EDGES);

    // 2) GEMM1: X1 = doc_embeds @ W1
    {
        dim3 grid(HID_CH / 64, (N_NODES + 63) / 64);
        gemm_kernel<<<grid, 256, 0, stream>>>(doc_embeds, W1, X1, N_NODES, HID_CH, IN_CH);
    }

    // 3) gather layer 1 (+self-loop +bias +relu) -> H1
    gather_kernel<4><<<(N_NODES + 3) / 4, 256, 0, stream>>>(
        X1, dinv, rowptr, srcs, b1, H1, N_NODES, 1);

    // 4) GEMM2: X2 = H1 @ W2
    {
        dim3 grid(OUT_CH / 64, (N_NODES + 63) / 64);
        gemm_kernel<<<grid, 256, 0, stream>>>(H1, W2, X2, N_NODES, OUT_CH, HID_CH);
    }

    // 5) gather layer 2 (+self-loop +bias) -> d_out
    gather_kernel<2><<<(N_NODES + 3) / 4, 256, 0, stream>>>(
        X2, dinv, rowptr, srcs, b2, out, N_NODES, 0);
}

// Round 4
// 227.553 us; speedup vs baseline: 7.8308x; 1.1884x over previous
//
#include <hip/hip_runtime.h>
#include <math.h>

#define N_NODES 20000
#define N_EDGES 320000
#define IN_CH   256
#define HID_CH  256
#define OUT_CH  128

#define SCAN_TILE 256
#define N_TILES ((N_NODES + SCAN_TILE - 1) / SCAN_TILE)   // 79

typedef __attribute__((ext_vector_type(8))) short short8;
typedef __attribute__((ext_vector_type(8))) unsigned short ushort8;
typedef __attribute__((ext_vector_type(4))) unsigned short ushort4v;
typedef __attribute__((ext_vector_type(4))) float floatx4;

// bf16 round-to-nearest-even helpers (bit-level, no NaN handling needed here)
static __device__ __forceinline__ unsigned short f2bf(float f) {
    unsigned int u = __float_as_uint(f);
    u += 0x7FFFu + ((u >> 16) & 1u);
    return (unsigned short)(u >> 16);
}
static __device__ __forceinline__ float bf2f(unsigned short h) {
    return __uint_as_float(((unsigned int)h) << 16);
}

// ---------------------------------------------------------------------------
// degree (indegree, self-loop handled in dinv) via int atomics
// ---------------------------------------------------------------------------
__global__ void deg_kernel(const int* __restrict__ col, int* __restrict__ deg, int E) {
    int i = blockIdx.x * blockDim.x + threadIdx.x;
    if (i < E) atomicAdd(&deg[col[i]], 1);
}

// ---------------------------------------------------------------------------
// multi-block scan phase 1: per-tile exclusive scan + tile partials
// ---------------------------------------------------------------------------
__global__ __launch_bounds__(SCAN_TILE)
void block_scan_kernel(const int* __restrict__ deg, int* __restrict__ tile_excl,
                       int* __restrict__ partials, int n) {
    __shared__ int s[SCAN_TILE];
    const int tid = threadIdx.x;
    const int i = blockIdx.x * SCAN_TILE + tid;
    int v = (i < n) ? deg[i] : 0;
    s[tid] = v;
    __syncthreads();
    for (int off = 1; off < SCAN_TILE; off <<= 1) {
        int t = (tid >= off) ? s[tid - off] : 0;
        __syncthreads();
        if (tid >= off) s[tid] += t;
        __syncthreads();
    }
    if (i < n) tile_excl[i] = s[tid] - v;
    if (tid == SCAN_TILE - 1) partials[blockIdx.x] = s[tid];
}

// ---------------------------------------------------------------------------
// phase 2: scan the N_TILES partials (single tiny block)
// ---------------------------------------------------------------------------
__global__ __launch_bounds__(128)
void partial_scan_kernel(const int* __restrict__ partials, int* __restrict__ offsets,
                         int ntiles) {
    __shared__ int s[128];
    const int tid = threadIdx.x;
    int v = (tid < ntiles) ? partials[tid] : 0;
    s[tid] = v;
    __syncthreads();
    for (int off = 1; off < 128; off <<= 1) {
        int t = (tid >= off) ? s[tid - off] : 0;
        __syncthreads();
        if (tid >= off) s[tid] += t;
        __syncthreads();
    }
    if (tid < ntiles) offsets[tid] = s[tid] - v;
}

// ---------------------------------------------------------------------------
// phase 3: rowptr/cursor + fused dinv
// ---------------------------------------------------------------------------
__global__ __launch_bounds__(SCAN_TILE)
void finalize_scan_kernel(const int* __restrict__ tile_excl, const int* __restrict__ offsets,
                          const int* __restrict__ deg, int* __restrict__ rowptr,
                          int* __restrict__ cursor, float* __restrict__ dinv, int n) {
    const int i = blockIdx.x * SCAN_TILE + threadIdx.x;
    if (i < n) {
        int r = tile_excl[i] + offsets[blockIdx.x];
        rowptr[i] = r;
        cursor[i] = r;
        dinv[i] = 1.0f / sqrtf((float)(deg[i] + 1));
    }
    if (i == 0) rowptr[n] = N_EDGES;
}

// ---------------------------------------------------------------------------
// fill CSR: srcs[pos] = row[e], bucketed by destination col[e]
// ---------------------------------------------------------------------------
__global__ void fill_kernel(const int* __restrict__ row, const int* __restrict__ col,
                            int* __restrict__ cursor, int* __restrict__ srcs, int E) {
    int i = blockIdx.x * blockDim.x + threadIdx.x;
    if (i < E) {
        int p = atomicAdd(&cursor[col[i]], 1);
        srcs[p] = row[i];
    }
}

// ---------------------------------------------------------------------------
// split-bf16 decompose: x = hi + lo (both bf16). Elementwise, float4/thread.
// n must be a multiple of 4 (5.12M here).
// ---------------------------------------------------------------------------
__global__ void decomp_kernel(const float* __restrict__ in, unsigned short* __restrict__ hi,
                              unsigned short* __restrict__ lo, int n4) {
    int i = blockIdx.x * blockDim.x + threadIdx.x;
    if (i >= n4) return;
    float4 x = *(const float4*)(in + (size_t)i * 4);
    ushort4v h, l;
    h.x = f2bf(x.x); l.x = f2bf(x.x - bf2f(h.x));
    h.y = f2bf(x.y); l.y = f2bf(x.y - bf2f(h.y));
    h.z = f2bf(x.z); l.z = f2bf(x.z - bf2f(h.z));
    h.w = f2bf(x.w); l.w = f2bf(x.w - bf2f(h.w));
    *(ushort4v*)(hi + (size_t)i * 4) = h;
    *(ushort4v*)(lo + (size_t)i * 4) = l;
}

// ---------------------------------------------------------------------------
// transpose + decompose weights: W[K][N] -> Wt{hi,lo}[N][K]
// ---------------------------------------------------------------------------
__global__ void decompT_kernel(const float* __restrict__ W, unsigned short* __restrict__ hi,
                               unsigned short* __restrict__ lo, int K, int N) {
    int i = blockIdx.x * blockDim.x + threadIdx.x;
    if (i >= K * N) return;
    int k = i / N, n = i % N;
    float x = W[i];
    unsigned short h = f2bf(x);
    unsigned short l = f2bf(x - bf2f(h));
    hi[(size_t)n * K + k] = h;
    lo[(size_t)n * K + k] = l;
}

// ---------------------------------------------------------------------------
// split-bf16 MFMA GEMM: C[M,N] = A[M,K] @ B[K,N], K=256 fixed.
// A given as hi/lo bf16 [M][K]; B given TRANSPOSED hi/lo bf16 [N][K].
// 3-term compensation: hi*hi + hi*lo + lo*hi (~fp32 precision).
// 128x128 block tile, BK=32, 256 threads = 4 waves (2x2), 4x4 MFMA tiles/wave.
// ---------------------------------------------------------------------------
#define GK 256
__global__ __launch_bounds__(256)
void gemm_mfma_kernel(const unsigned short* __restrict__ Ahi, const unsigned short* __restrict__ Alo,
                      const unsigned short* __restrict__ Bthi, const unsigned short* __restrict__ Btlo,
                      float* __restrict__ C, int M, int N) {
    __shared__ unsigned short As[2][128][40];   // [hi/lo][m][k], pad 32->40 (2-way max)
    __shared__ unsigned short Bs[2][128][40];   // [hi/lo][n][k]
    const int tid = threadIdx.x;
    const int m0 = blockIdx.y * 128;
    const int n0 = blockIdx.x * 128;
    const int lane = tid & 63;
    const int wave = tid >> 6;
    const int wr = (wave >> 1) * 64;   // wave row offset within block tile
    const int wc = (wave & 1) * 64;    // wave col offset
    const int lm = lane & 15;
    const int lk = (lane >> 4) * 8;    // k-offset of this lane's 8 elements

    floatx4 acc[4][4];
#pragma unroll
    for (int i = 0; i < 4; ++i)
#pragma unroll
        for (int j = 0; j < 4; ++j) acc[i][j] = (floatx4){0.f, 0.f, 0.f, 0.f};

    for (int k0 = 0; k0 < GK; k0 += 32) {
        // stage A and B tiles (hi+lo): 128 rows x 32 k each, ushort8 chunks
#pragma unroll
        for (int c = 0; c < 2; ++c) {
            int ch = tid + c * 256;          // 0..511
            int r = ch >> 2;                 // 0..127
            int ko = (ch & 3) * 8;           // 0,8,16,24
            size_t ga = (size_t)(m0 + r) * GK + k0 + ko;
            ushort8 vh = {}, vl = {};
            if (m0 + r < M) {
                vh = *(const ushort8*)(Ahi + ga);
                vl = *(const ushort8*)(Alo + ga);
            }
            *(ushort8*)&As[0][r][ko] = vh;
            *(ushort8*)&As[1][r][ko] = vl;
            size_t gb = (size_t)(n0 + r) * GK + k0 + ko;   // N multiple of 128
            *(ushort8*)&Bs[0][r][ko] = *(const ushort8*)(Bthi + gb);
            *(ushort8*)&Bs[1][r][ko] = *(const ushort8*)(Btlo + gb);
        }
        __syncthreads();

        short8 ah[4], al[4], bh[4], bl[4];
#pragma unroll
        for (int i = 0; i < 4; ++i) {
            ah[i] = *(const short8*)&As[0][wr + i * 16 + lm][lk];
            al[i] = *(const short8*)&As[1][wr + i * 16 + lm][lk];
        }
#pragma unroll
        for (int j = 0; j < 4; ++j) {
            bh[j] = *(const short8*)&Bs[0][wc + j * 16 + lm][lk];
            bl[j] = *(const short8*)&Bs[1][wc + j * 16 + lm][lk];
        }
#pragma unroll
        for (int i = 0; i < 4; ++i)
#pragma unroll
            for (int j = 0; j < 4; ++j) {
                acc[i][j] = __builtin_amdgcn_mfma_f32_16x16x32_bf16(ah[i], bh[j], acc[i][j], 0, 0, 0);
                acc[i][j] = __builtin_amdgcn_mfma_f32_16x16x32_bf16(ah[i], bl[j], acc[i][j], 0, 0, 0);
                acc[i][j] = __builtin_amdgcn_mfma_f32_16x16x32_bf16(al[i], bh[j], acc[i][j], 0, 0, 0);
            }
        __syncthreads();
    }

    // epilogue: C/D layout col = lane&15, row = (lane>>4)*4 + reg
#pragma unroll
    for (int i = 0; i < 4; ++i) {
#pragma unroll
        for (int r = 0; r < 4; ++r) {
            int rowi = m0 + wr + i * 16 + (lane >> 4) * 4 + r;
            if (rowi < M) {
#pragma unroll
                for (int j = 0; j < 4; ++j) {
                    C[(size_t)rowi * N + n0 + wc + j * 16 + lm] = acc[i][j][r];
                }
            }
        }
    }
}

// ---------------------------------------------------------------------------
// gather aggregation: one wave per destination node, lane holds VEC channels.
// 4-wide edge unroll for memory-level parallelism.
// MODE 0: write fp32 out. MODE 1: relu + write bf16 hi/lo (for next GEMM).
// ---------------------------------------------------------------------------
template <int VEC, int MODE>
__global__ __launch_bounds__(256)
void gather_kernel(const float* __restrict__ X, const float* __restrict__ dinv,
                   const int* __restrict__ rowptr, const int* __restrict__ srcs,
                   const float* __restrict__ bias, float* __restrict__ outf,
                   unsigned short* __restrict__ outhi, unsigned short* __restrict__ outlo,
                   int n) {
    const int C = VEC * 64;
    const int node = blockIdx.x * (blockDim.x >> 6) + (threadIdx.x >> 6);
    const int lane = threadIdx.x & 63;
    if (node >= n) return;
    const int beg = rowptr[node];
    const int end = rowptr[node + 1];

    float acc[VEC];
#pragma unroll
    for (int i = 0; i < VEC; ++i) acc[i] = 0.f;

    int e = beg;
    for (; e + 4 <= end; e += 4) {
        int r0 = srcs[e + 0], r1 = srcs[e + 1], r2 = srcs[e + 2], r3 = srcs[e + 3];
        float w0 = dinv[r0], w1 = dinv[r1], w2 = dinv[r2], w3 = dinv[r3];
        const float* p0 = X + (size_t)r0 * C + lane * VEC;
        const float* p1 = X + (size_t)r1 * C + lane * VEC;
        const float* p2 = X + (size_t)r2 * C + lane * VEC;
        const float* p3 = X + (size_t)r3 * C + lane * VEC;
        if constexpr (VEC == 4) {
            float4 v0 = *(const float4*)p0;
            float4 v1 = *(const float4*)p1;
            float4 v2 = *(const float4*)p2;
            float4 v3 = *(const float4*)p3;
            acc[0] += w0 * v0.x + w1 * v1.x + w2 * v2.x + w3 * v3.x;
            acc[1] += w0 * v0.y + w1 * v1.y + w2 * v2.y + w3 * v3.y;
            acc[2] += w0 * v0.z + w1 * v1.z + w2 * v2.z + w3 * v3.z;
            acc[3] += w0 * v0.w + w1 * v1.w + w2 * v2.w + w3 * v3.w;
        } else {
            float2 v0 = *(const float2*)p0;
            float2 v1 = *(const float2*)p1;
            float2 v2 = *(const float2*)p2;
            float2 v3 = *(const float2*)p3;
            acc[0] += w0 * v0.x + w1 * v1.x + w2 * v2.x + w3 * v3.x;
            acc[1] += w0 * v0.y + w1 * v1.y + w2 * v2.y + w3 * v3.y;
        }
    }
    for (; e < end; ++e) {
        int r = srcs[e];
        float w = dinv[r];
        const float* xp = X + (size_t)r * C + lane * VEC;
        if constexpr (VEC == 4) {
            float4 v = *(const float4*)xp;
            acc[0] += w * v.x; acc[1] += w * v.y;
            acc[2] += w * v.z; acc[3] += w * v.w;
        } else {
            float2 v = *(const float2*)xp;
            acc[0] += w * v.x; acc[1] += w * v.y;
        }
    }

    const float dc = dinv[node];
    const float* xs = X + (size_t)node * C + lane * VEC;
    const float* bp = bias + lane * VEC;

    float o[VEC];
    if constexpr (VEC == 4) {
        float4 vs = *(const float4*)xs;
        float4 bb = *(const float4*)bp;
        o[0] = dc * (acc[0] + dc * vs.x) + bb.x;
        o[1] = dc * (acc[1] + dc * vs.y) + bb.y;
        o[2] = dc * (acc[2] + dc * vs.z) + bb.z;
        o[3] = dc * (acc[3] + dc * vs.w) + bb.w;
    } else {
        float2 vs = *(const float2*)xs;
        float2 bb = *(const float2*)bp;
        o[0] = dc * (acc[0] + dc * vs.x) + bb.x;
        o[1] = dc * (acc[1] + dc * vs.y) + bb.y;
    }

    if constexpr (MODE == 1) {
        // relu + split-bf16 decompose, write hi/lo
#pragma unroll
        for (int i = 0; i < VEC; ++i) o[i] = fmaxf(o[i], 0.f);
        ushort4v h, l;
        h.x = f2bf(o[0]); l.x = f2bf(o[0] - bf2f(h.x));
        h.y = f2bf(o[1]); l.y = f2bf(o[1] - bf2f(h.y));
        h.z = f2bf(o[2]); l.z = f2bf(o[2] - bf2f(h.z));
        h.w = f2bf(o[3]); l.w = f2bf(o[3] - bf2f(h.w));
        *(ushort4v*)(outhi + (size_t)node * C + lane * VEC) = h;
        *(ushort4v*)(outlo + (size_t)node * C + lane * VEC) = l;
    } else {
        float* op = outf + (size_t)node * C + lane * VEC;
        if constexpr (VEC == 4) {
            *(float4*)op = make_float4(o[0], o[1], o[2], o[3]);
        } else {
            *(float2*)op = make_float2(o[0], o[1]);
        }
    }
}

// ---------------------------------------------------------------------------
extern "C" void kernel_launch(void* const* d_in, const int* in_sizes, int n_in,
                              void* d_out, int out_size, void* d_ws, size_t ws_size,
                              hipStream_t stream) {
    const float* doc_embeds = (const float*)d_in[0];   // [20000,256]
    const int*   edge_index = (const int*)d_in[1];     // [2,320000]
    const float* W1 = (const float*)d_in[2];           // [256,256]
    const float* b1 = (const float*)d_in[3];           // [256]
    const float* W2 = (const float*)d_in[4];           // [256,128]
    const float* b2 = (const float*)d_in[5];           // [128]
    float* out = (float*)d_out;                        // [20000,128]

    const int* row = edge_index;            // sources
    const int* col = edge_index + N_EDGES;  // destinations

    // ---------------- workspace layout (256B aligned) ----------------
    char* ws = (char*)d_ws;
    auto align_up = [](size_t x) { return (x + 255) / 256 * 256; };
    const size_t XHL = (size_t)N_NODES * HID_CH * 2;   // 10.24 MB (one bf16 plane)

    unsigned short* Xhi  = (unsigned short*)(ws);                 // doc_embeds hi
    unsigned short* Xlo  = (unsigned short*)(ws + XHL);           // doc_embeds lo
    float*          X1   = (float*)(ws + 2 * XHL);                // gemm1 out fp32 (20.48 MB)
    unsigned short* H1hi = (unsigned short*)(ws + 4 * XHL);       // gather1 out hi
    unsigned short* H1lo = (unsigned short*)(ws + 5 * XHL);       // gather1 out lo
    float*          X2   = (float*)(ws);                          // gemm2 out fp32, reuses Xhi/Xlo
    char* meta = ws + 6 * XHL;
    unsigned short* W1thi = (unsigned short*)(meta); meta += align_up((size_t)IN_CH * HID_CH * 2);
    unsigned short* W1tlo = (unsigned short*)(meta); meta += align_up((size_t)IN_CH * HID_CH * 2);
    unsigned short* W2thi = (unsigned short*)(meta); meta += align_up((size_t)HID_CH * OUT_CH * 2);
    unsigned short* W2tlo = (unsigned short*)(meta); meta += align_up((size_t)HID_CH * OUT_CH * 2);
    int*   deg       = (int*)(meta);   meta += align_up((size_t)N_NODES * 4);
    int*   tile_excl = (int*)(meta);   meta += align_up((size_t)N_NODES * 4);
    int*   partials  = (int*)(meta);   meta += align_up((size_t)N_TILES * 4);
    int*   offsets   = (int*)(meta);   meta += align_up((size_t)N_TILES * 4);
    int*   rowptr    = (int*)(meta);   meta += align_up((size_t)(N_NODES + 1) * 4);
    int*   cursor    = (int*)(meta);   meta += align_up((size_t)(N_NODES + 1) * 4);
    float* dinv      = (float*)(meta); meta += align_up((size_t)N_NODES * 4);
    int*   srcs      = (int*)(meta);

    // ---------------- graph prep ----------------
    hipMemsetAsync(deg, 0, (size_t)N_NODES * 4, stream);
    deg_kernel<<<(N_EDGES + 255) / 256, 256, 0, stream>>>(col, deg, N_EDGES);
    block_scan_kernel<<<N_TILES, SCAN_TILE, 0, stream>>>(deg, tile_excl, partials, N_NODES);
    partial_scan_kernel<<<1, 128, 0, stream>>>(partials, offsets, N_TILES);
    finalize_scan_kernel<<<N_TILES, SCAN_TILE, 0, stream>>>(
        tile_excl, offsets, deg, rowptr, cursor, dinv, N_NODES);
    fill_kernel<<<(N_EDGES + 255) / 256, 256, 0, stream>>>(row, col, cursor, srcs, N_EDGES);

    // ---------------- decompose inputs ----------------
    {
        int n4 = N_NODES * IN_CH / 4;
        decomp_kernel<<<(n4 + 255) / 256, 256, 0, stream>>>(doc_embeds, Xhi, Xlo, n4);
        decompT_kernel<<<(IN_CH * HID_CH + 255) / 256, 256, 0, stream>>>(W1, W1thi, W1tlo, IN_CH, HID_CH);
        decompT_kernel<<<(HID_CH * OUT_CH + 255) / 256, 256, 0, stream>>>(W2, W2thi, W2tlo, HID_CH, OUT_CH);
    }

    // ---------------- layer 1 ----------------
    {
        dim3 grid(HID_CH / 128, (N_NODES + 127) / 128);  // (2, 157)
        gemm_mfma_kernel<<<grid, 256, 0, stream>>>(Xhi, Xlo, W1thi, W1tlo, X1, N_NODES, HID_CH);
    }
    gather_kernel<4, 1><<<(N_NODES + 3) / 4, 256, 0, stream>>>(
        X1, dinv, rowptr, srcs, b1, nullptr, H1hi, H1lo, N_NODES);

    // ---------------- layer 2 ----------------
    {
        dim3 grid(OUT_CH / 128, (N_NODES + 127) / 128);  // (1, 157)
        gemm_mfma_kernel<<<grid, 256, 0, stream>>>(H1hi, H1lo, W2thi, W2tlo, X2, N_NODES, OUT_CH);
    }
    gather_kernel<2, 0><<<(N_NODES + 3) / 4, 256, 0, stream>>>(
        X2, dinv, rowptr, srcs, b2, out, nullptr, nullptr, N_NODES);
}